// Round 3
// baseline (143.108 us; speedup 1.0000x reference)
//
#include <hip/hip_runtime.h>
#include <hip/hip_bf16.h>
#include <math.h>

#define NB 2
#define CIN 256
#define NPOS 4096          // 64*64
#define HID 128
#define NHEAD 4
#define DHEAD 32
#define NBH 8
#define NSPLIT 8
#define QSCALE 0.2550348676144781f   // 32^-0.5 * log2(e), folded into W_q

typedef __bf16 bf16;
typedef __attribute__((ext_vector_type(8))) __bf16 bf16x8;
typedef __attribute__((ext_vector_type(4))) __bf16 bf16x4;
typedef __attribute__((ext_vector_type(4))) float f32x4;

union B8 { bf16x8 v; bf16x4 h[2]; };

// ws layout (byte offsets), total 24,379,392 B:
// aop overlays xt — xt is dead after qkv_kernel, aop first written by fattn_kernel.
#define QB_OFF  0u            // qb  bf16 [8][4096][32]     2 MB  (W_q pre-scaled by QSCALE)
#define KB_OFF  2097152u      // kb  bf16 [8][4096][32]     2 MB
#define VT_OFF  4194304u      // vtb bf16 [8][32][4096]     2 MB  (V transposed)
#define LP_OFF  6291456u      // lp  f32  [8][8][4096]      1 MB
#define WB_OFF  7340032u      // wb  bf16 [384][256]        192 KB
#define WOB_OFF 7536640u      // wob bf16 [256][128]        64 KB
#define XT_OFF  7602176u      // xt  bf16 [2][4096][256]    4 MB   (dead after qkv)
#define AOP_OFF 7602176u      // aop bf16 [8][2][4096][128] 16 MB  (overlays xt)

// ---------------- Kernel 0: prep — transpose x to bf16 [b][i][c]; cast weights ----------------
__global__ __launch_bounds__(256) void prep_kernel(const float* __restrict__ x,
                                                   const float* __restrict__ wqkv,
                                                   const float* __restrict__ wout,
                                                   bf16* __restrict__ xt,
                                                   bf16* __restrict__ wb,
                                                   bf16* __restrict__ wob) {
    const int t = threadIdx.x;
    if (blockIdx.y == 4) {
        int tid = blockIdx.x * 256 + t;           // 0..16383
        if (blockIdx.z == 0) {
            #pragma unroll
            for (int u = 0; u < 6; ++u) {
                int idx = tid * 6 + u;            // 98304 = 384*256 exactly
                float v = wqkv[idx];
                if (idx < 32768) v *= QSCALE;     // rows 0..127 = W_q
                wb[idx] = (bf16)v;
            }
        } else {
            wob[tid * 2]     = (bf16)wout[tid * 2];     // 32768 = 256*128
            wob[tid * 2 + 1] = (bf16)wout[tid * 2 + 1];
        }
        return;
    }
    const int b  = blockIdx.z;
    const int c0 = blockIdx.y * 64;
    const int i0 = blockIdx.x * 64;
    __shared__ float Ts[64][65];
    const float* xb = x + (size_t)b * CIN * NPOS;
    #pragma unroll
    for (int u = 0; u < 4; ++u) {
        int c = (t >> 4) + u * 16;
        int i = (t & 15) * 4;
        float4 v = *(const float4*)(xb + (size_t)(c0 + c) * NPOS + i0 + i);
        Ts[c][i] = v.x; Ts[c][i + 1] = v.y; Ts[c][i + 2] = v.z; Ts[c][i + 3] = v.w;
    }
    __syncthreads();
    int i  = t & 63;
    int cc = (t >> 6) * 16;
    B8 o0, o1;
    #pragma unroll
    for (int j = 0; j < 8; ++j) {
        o0.v[j] = (bf16)Ts[cc + j][i];
        o1.v[j] = (bf16)Ts[cc + 8 + j][i];
    }
    bf16* dst = xt + ((size_t)b * NPOS + i0 + i) * CIN + c0 + cc;
    *(bf16x8*)dst       = o0.v;
    *(bf16x8*)(dst + 8) = o1.v;
}

// ---------------- Kernel 1: qkv MFMA GEMM ----------------
__global__ __launch_bounds__(256) void qkv_kernel(const bf16* __restrict__ xt,
                                                  const bf16* __restrict__ wb,
                                                  bf16* __restrict__ qb,
                                                  bf16* __restrict__ kb,
                                                  bf16* __restrict__ vtb) {
    const int i0 = blockIdx.x * 64;
    const int ot = blockIdx.y * 64;
    const int b  = blockIdx.z;
    const int t  = threadIdx.x;
    const int w  = t >> 6;
    const int lane = t & 63;
    const int quad = lane >> 4;
    const int li   = lane & 15;

    __shared__ bf16 Bs[64][36];   // [i_loc][k]

    f32x4 acc[4];
    #pragma unroll
    for (int n = 0; n < 4; ++n) acc[n] = (f32x4){0.f, 0.f, 0.f, 0.f};

    const bf16* xrow = xt + ((size_t)b * NPOS + i0) * CIN;
    const int si = t >> 2;            // 0..63
    const int sk = (t & 3) * 8;       // 0,8,16,24

    for (int k0 = 0; k0 < CIN; k0 += 32) {
        __syncthreads();
        B8 g0;
        g0.v = *(const bf16x8*)(xrow + (size_t)si * CIN + k0 + sk);
        *(bf16x4*)&Bs[si][sk]     = g0.h[0];
        *(bf16x4*)&Bs[si][sk + 4] = g0.h[1];
        __syncthreads();
        bf16x8 afrag = *(const bf16x8*)(wb + (size_t)(ot + w * 16 + li) * CIN + k0 + quad * 8);
        #pragma unroll
        for (int n = 0; n < 4; ++n) {
            B8 bf;
            bf.h[0] = *(const bf16x4*)&Bs[n * 16 + li][quad * 8];
            bf.h[1] = *(const bf16x4*)&Bs[n * 16 + li][quad * 8 + 4];
            acc[n] = __builtin_amdgcn_mfma_f32_16x16x32_bf16(afrag, bf.v, acc[n], 0, 0, 0);
        }
    }

    const int obase = ot + w * 16;
    const int sect  = obase >> 7;            // 0=q 1=k 2=v
    const int oo    = obase & 127;
    const int h     = oo >> 5;
    const int dbase = (oo & 31) + quad * 4;
    const int bh    = b * NHEAD + h;

    #pragma unroll
    for (int n = 0; n < 4; ++n) {
        int i = i0 + n * 16 + li;
        f32x4 v = acc[n];
        if (sect <= 1) {
            bf16x4 pk;
            #pragma unroll
            for (int r = 0; r < 4; ++r) pk[r] = (bf16)v[r];
            bf16* base = (sect == 0) ? qb : kb;
            *(bf16x4*)(base + ((size_t)bh * NPOS + i) * DHEAD + dbase) = pk;
        } else {
            #pragma unroll
            for (int r = 0; r < 4; ++r)
                vtb[((size_t)bh * DHEAD + dbase + r) * NPOS + i] = (bf16)v[r];
        }
    }
}

// ---------------- Kernel 2: MFMA flash attention, register-pipelined loads ----------------
// R8: occupancy is register-capped at 4 waves/SIMD (128-reg unified budget under
// (256,4); R6 proved <=64 spills). So attack per-iteration EXPOSED latency with
// distance-1 register prefetch instead of TLP:
//   QK(it) [kf loaded last iter] -> reissue kf=K(it+1) -> PV(it-1) [vf loaded last
//   iter] -> reissue vf=V(it) -> exp(it)+plds write.
// Load-after-use reg reuse = zero extra registers; compiler emits counted vmcnt.
// exp(it) sits after PV's 12 MFMAs, covering QK MFMA latency. No barriers at all
// (plds is wave-private). #pragma unroll 1 keeps the compiler from double-buffering
// registers past the budget.
__global__ __launch_bounds__(256, 4) void fattn_kernel(const bf16* __restrict__ qb,
                                                       const bf16* __restrict__ kb,
                                                       const bf16* __restrict__ vtb,
                                                       bf16* __restrict__ aop,
                                                       float* __restrict__ lpart) {
    const int id    = blockIdx.x;
    const int g     = id & 63;
    const int iblk  = id >> 6;           // 0..31
    const int bh    = g >> 3;
    const int split = g & 7;
    const int w     = threadIdx.x >> 6;
    const int lane  = threadIdx.x & 63;
    const int quad  = lane >> 4;
    const int li    = lane & 15;
    const int i0    = iblk * 128 + w * 32;
    const int j_lo  = split * 512;

    const bf16* qrow = qb + (size_t)bh * NPOS * DHEAD;
    const bf16x8 qf0 = *(const bf16x8*)(qrow + (size_t)(i0 + li) * DHEAD + quad * 8);
    const bf16x8 qf1 = *(const bf16x8*)(qrow + (size_t)(i0 + 16 + li) * DHEAD + quad * 8);
    const bf16* kbase  = kb  + (size_t)bh * NPOS * DHEAD;
    const bf16* vtbase = vtb + (size_t)bh * DHEAD * NPOS;
    // V row pointers (row index fixed per lane; column = j)
    const bf16* vrow0 = vtbase + (size_t)li        * NPOS + quad * 8;
    const bf16* vrow1 = vtbase + (size_t)(16 + li) * NPOS + quad * 8;

    bf16x8 ones;
    #pragma unroll
    for (int j = 0; j < 8; ++j) ones[j] = (bf16)1.0f;

    f32x4 o00 = {0.f,0.f,0.f,0.f}, o01 = {0.f,0.f,0.f,0.f};
    f32x4 o10 = {0.f,0.f,0.f,0.f}, o11 = {0.f,0.f,0.f,0.f};
    f32x4 l0  = {0.f,0.f,0.f,0.f}, l1  = {0.f,0.f,0.f,0.f};
    __shared__ alignas(16) bf16 plds[4][32][72];   // [wave][i][j], 18,432 B, wave-private

    const f32x4 zero = {0.f,0.f,0.f,0.f};

    bf16x8 kf[4];   // K(it) fragments, loaded one iteration ahead
    bf16x8 vf[4];   // V(it-1) fragments for PV, loaded one iteration ahead

    auto load_k = [&](int j0) {
        #pragma unroll
        for (int tt = 0; tt < 4; ++tt)
            kf[tt] = *(const bf16x8*)(kbase + (size_t)(j0 + 16 * tt + li) * DHEAD + quad * 8);
    };
    auto load_v = [&](int j0) {
        vf[0] = *(const bf16x8*)(vrow0 + j0);
        vf[1] = *(const bf16x8*)(vrow1 + j0);
        vf[2] = *(const bf16x8*)(vrow0 + j0 + 32);
        vf[3] = *(const bf16x8*)(vrow1 + j0 + 32);
    };
    auto pv_mfma = [&]() {
        #pragma unroll
        for (int h2 = 0; h2 < 2; ++h2) {
            bf16x8 pf0 = *(const bf16x8*)&plds[w][li][h2 * 32 + quad * 8];
            bf16x8 pf1 = *(const bf16x8*)&plds[w][16 + li][h2 * 32 + quad * 8];
            l0  = __builtin_amdgcn_mfma_f32_16x16x32_bf16(ones, pf0, l0,  0, 0, 0);
            l1  = __builtin_amdgcn_mfma_f32_16x16x32_bf16(ones, pf1, l1,  0, 0, 0);
            o00 = __builtin_amdgcn_mfma_f32_16x16x32_bf16(vf[h2*2],   pf0, o00, 0, 0, 0);
            o01 = __builtin_amdgcn_mfma_f32_16x16x32_bf16(vf[h2*2+1], pf0, o01, 0, 0, 0);
            o10 = __builtin_amdgcn_mfma_f32_16x16x32_bf16(vf[h2*2],   pf1, o10, 0, 0, 0);
            o11 = __builtin_amdgcn_mfma_f32_16x16x32_bf16(vf[h2*2+1], pf1, o11, 0, 0, 0);
        }
    };
    auto exp_store = [&](const f32x4* s0, const f32x4* s1) {
        #pragma unroll
        for (int tt = 0; tt < 4; ++tt) {
            bf16x4 p0, p1;
            #pragma unroll
            for (int r = 0; r < 4; ++r) {
                p0[r] = (bf16)__builtin_amdgcn_exp2f(s0[tt][r]);
                p1[r] = (bf16)__builtin_amdgcn_exp2f(s1[tt][r]);
            }
            *(bf16x4*)&plds[w][li][16 * tt + quad * 4]      = p0;
            *(bf16x4*)&plds[w][16 + li][16 * tt + quad * 4] = p1;
        }
    };

    // ---- prologue: K(0) in flight ----
    load_k(j_lo);

    // ---- iter 0 (peeled, no PV) ----
    {
        f32x4 s0[4], s1[4];
        #pragma unroll
        for (int tt = 0; tt < 4; ++tt) {
            s0[tt] = __builtin_amdgcn_mfma_f32_16x16x32_bf16(kf[tt], qf0, zero, 0, 0, 0);
            s1[tt] = __builtin_amdgcn_mfma_f32_16x16x32_bf16(kf[tt], qf1, zero, 0, 0, 0);
        }
        load_k(j_lo + 64);      // K(1)
        load_v(j_lo);           // V(0), consumed by PV in iter 1
        exp_store(s0, s1);
    }

    // ---- steady state ----
    #pragma unroll 1
    for (int it = 1; it < 8; ++it) {
        const int j0 = j_lo + it * 64;
        f32x4 s0[4], s1[4];
        #pragma unroll
        for (int tt = 0; tt < 4; ++tt) {
            s0[tt] = __builtin_amdgcn_mfma_f32_16x16x32_bf16(kf[tt], qf0, zero, 0, 0, 0);
            s1[tt] = __builtin_amdgcn_mfma_f32_16x16x32_bf16(kf[tt], qf1, zero, 0, 0, 0);
        }
        load_k(j_lo + (it + (it < 7)) * 64);   // K(it+1), clamped (reload K(7) on last)
        pv_mfma();                              // PV(it-1) with vf=V(it-1), plds(it-1)
        load_v(j0);                             // V(it) for next iteration's PV
        exp_store(s0, s1);                      // exp(it) covered by PV MFMAs above
    }
    // ---- drain: PV(7) ----
    pv_mfma();

    const int b = bh >> 2, h = bh & 3;
    {
        const int i = i0 + li;
        bf16* dst = aop + (((size_t)(split * NB + b) * NPOS + i) * HID) + h * DHEAD;
        bf16x4 pk0, pk1;
        #pragma unroll
        for (int r = 0; r < 4; ++r) { pk0[r] = (bf16)o00[r]; pk1[r] = (bf16)o01[r]; }
        *(bf16x4*)(dst + quad * 4)      = pk0;
        *(bf16x4*)(dst + 16 + quad * 4) = pk1;
        if (quad == 0) lpart[((size_t)split * NBH + bh) * NPOS + i] = l0[0];
    }
    {
        const int i = i0 + 16 + li;
        bf16* dst = aop + (((size_t)(split * NB + b) * NPOS + i) * HID) + h * DHEAD;
        bf16x4 pk0, pk1;
        #pragma unroll
        for (int r = 0; r < 4; ++r) { pk0[r] = (bf16)o10[r]; pk1[r] = (bf16)o11[r]; }
        *(bf16x4*)(dst + quad * 4)      = pk0;
        *(bf16x4*)(dst + 16 + quad * 4) = pk1;
        if (quad == 0) lpart[((size_t)split * NBH + bh) * NPOS + i] = l1[0];
    }
}

// ---------------- Kernel 3: proj GEMM with fused split-combine in the staging path ----------------
__global__ __launch_bounds__(256) void proj_kernel(const bf16* __restrict__ aop,
                                                   const float* __restrict__ lpart,
                                                   const bf16* __restrict__ wob,
                                                   const float* __restrict__ bout,
                                                   float* __restrict__ y) {
    const int i0 = blockIdx.x * 64;
    const int ot = blockIdx.y * 64;
    const int b  = blockIdx.z;
    const int t  = threadIdx.x;
    const int w  = t >> 6;
    const int lane = t & 63;
    const int quad = lane >> 4;
    const int li   = lane & 15;

    __shared__ bf16 Bs[64][132];   // [i_loc][c]

    // staging with combine: thread = (row, 32-channel chunk)
    {
        const int row = t >> 2;          // 0..63
        const int cp  = (t & 3) * 32;    // 0,32,64,96 (one head each)
        const int gi  = i0 + row;
        const int h   = cp >> 5;

        float lsum = 0.f;
        #pragma unroll
        for (int s = 0; s < NSPLIT; ++s)
            lsum += lpart[((size_t)s * NBH + b * NHEAD + h) * NPOS + gi];
        const float invl = __builtin_amdgcn_rcpf(lsum);

        float vals[32];
        #pragma unroll
        for (int j = 0; j < 32; ++j) vals[j] = 0.f;
        #pragma unroll
        for (int s = 0; s < NSPLIT; ++s) {
            const bf16* src = aop + (((size_t)(s * NB + b) * NPOS + gi) * HID) + cp;
            #pragma unroll
            for (int m = 0; m < 4; ++m) {
                bf16x8 u = *(const bf16x8*)(src + m * 8);
                #pragma unroll
                for (int j = 0; j < 8; ++j) vals[m * 8 + j] += (float)u[j];
            }
        }
        #pragma unroll
        for (int m = 0; m < 4; ++m) {
            B8 pk;
            #pragma unroll
            for (int j = 0; j < 8; ++j) pk.v[j] = (bf16)(vals[m * 8 + j] * invl);
            *(bf16x8*)&Bs[row][cp + m * 8] = pk.v;
        }
    }
    __syncthreads();

    f32x4 acc[4];
    #pragma unroll
    for (int n = 0; n < 4; ++n) acc[n] = (f32x4){0.f, 0.f, 0.f, 0.f};

    #pragma unroll
    for (int k0 = 0; k0 < HID; k0 += 32) {
        bf16x8 afrag = *(const bf16x8*)(wob + (size_t)(ot + w * 16 + li) * HID + k0 + quad * 8);
        #pragma unroll
        for (int n = 0; n < 4; ++n) {
            B8 bf;
            bf.h[0] = *(const bf16x4*)&Bs[n * 16 + li][k0 + quad * 8];
            bf.h[1] = *(const bf16x4*)&Bs[n * 16 + li][k0 + quad * 8 + 4];
            acc[n] = __builtin_amdgcn_mfma_f32_16x16x32_bf16(afrag, bf.v, acc[n], 0, 0, 0);
        }
    }

    float bias[4];
    #pragma unroll
    for (int r = 0; r < 4; ++r) bias[r] = bout[ot + w * 16 + quad * 4 + r];
    float* yb = y + (size_t)b * CIN * NPOS;
    #pragma unroll
    for (int n = 0; n < 4; ++n) {
        int i = i0 + n * 16 + li;
        #pragma unroll
        for (int r = 0; r < 4; ++r)
            yb[(size_t)(ot + w * 16 + quad * 4 + r) * NPOS + i] = acc[n][r] + bias[r];
    }
}

extern "C" void kernel_launch(void* const* d_in, const int* in_sizes, int n_in,
                              void* d_out, int out_size, void* d_ws, size_t ws_size,
                              hipStream_t stream) {
    const float* x    = (const float*)d_in[0];
    const float* wqkv = (const float*)d_in[1];
    const float* wout = (const float*)d_in[2];
    const float* bout = (const float*)d_in[3];
    float* y = (float*)d_out;
    char* ws = (char*)d_ws;

    bf16*  qb  = (bf16*)(ws + QB_OFF);
    bf16*  kb  = (bf16*)(ws + KB_OFF);
    bf16*  vtb = (bf16*)(ws + VT_OFF);
    float* lp  = (float*)(ws + LP_OFF);
    bf16*  wb  = (bf16*)(ws + WB_OFF);
    bf16*  wob = (bf16*)(ws + WOB_OFF);
    bf16*  xt  = (bf16*)(ws + XT_OFF);
    bf16*  aop = (bf16*)(ws + AOP_OFF);   // overlays xt (dead after qkv)

    prep_kernel<<<dim3(64, 5, 2), 256, 0, stream>>>(x, wqkv, wout, xt, wb, wob);
    qkv_kernel<<<dim3(64, 6, 2), 256, 0, stream>>>(xt, wb, qb, kb, vtb);
    fattn_kernel<<<dim3(2048), 256, 0, stream>>>(qb, kb, vtb, aop, lp);
    proj_kernel<<<dim3(64, 4, 2), 256, 0, stream>>>(aop, lp, wob, bout, y);
}

// Round 4
// 142.924 us; speedup vs baseline: 1.0013x; 1.0013x over previous
//
#include <hip/hip_runtime.h>
#include <hip/hip_bf16.h>
#include <math.h>

#define NB 2
#define CIN 256
#define NPOS 4096          // 64*64
#define HID 128
#define NHEAD 4
#define DHEAD 32
#define NBH 8
#define NSPLIT 8
#define QSCALE 0.2550348676144781f   // 32^-0.5 * log2(e), applied in qkv epilogue

typedef __bf16 bf16;
typedef __attribute__((ext_vector_type(8))) __bf16 bf16x8;
typedef __attribute__((ext_vector_type(4))) __bf16 bf16x4;
typedef __attribute__((ext_vector_type(4))) float f32x4;

union B8 { bf16x8 v; bf16x4 h[2]; };

// ws layout (byte offsets), total 24,117,248 B (R9: prep/xt/wb/wob eliminated):
#define QB_OFF  0u            // qb  bf16 [8][4096][32]     2 MB
#define KB_OFF  2097152u      // kb  bf16 [8][4096][32]     2 MB
#define VT_OFF  4194304u      // vtb bf16 [8][32][4096]     2 MB  (V transposed)
#define LP_OFF  6291456u      // lp  f32  [8][8][4096]      1 MB
#define AOP_OFF 7340032u      // aop bf16 [8][2][4096][128] 16 MB

// ---------------- Kernel 1: qkv MFMA GEMM straight from f32 inputs ----------------
// R9: prep eliminated. B-tile staged from x (f32 [c][i], i-contiguous -> coalesced
// float4 reads) with in-LDS write-transpose (b16 writes, stride 68: ~2-way banks).
// A-frags cvt'd inline from f32 wqkv. BK=64 (4 K-steps), next-tile register
// prefetch across compute. Tile 32i x 64o -> grid 1536 = 6 blocks/CU.
__global__ __launch_bounds__(256) void qkv_kernel(const float* __restrict__ x,
                                                  const float* __restrict__ wqkv,
                                                  bf16* __restrict__ qb,
                                                  bf16* __restrict__ kb,
                                                  bf16* __restrict__ vtb) {
    const int i0 = blockIdx.x * 32;
    const int ot = blockIdx.y * 64;
    const int b  = blockIdx.z;
    const int t  = threadIdx.x;
    const int w  = t >> 6;
    const int lane = t & 63;
    const int quad = lane >> 4;
    const int li   = lane & 15;

    __shared__ bf16 Bs[32][68];   // [i_loc][k], stride 68 elem = 136B (b64-aligned rows)

    const float* xb = x + (size_t)b * CIN * NPOS;
    const int sk = t >> 2;          // 0..63  (k within step)
    const int si = (t & 3) * 8;     // 0,8,16,24 (i chunk)

    f32x4 acc[2];
    acc[0] = (f32x4){0.f,0.f,0.f,0.f};
    acc[1] = (f32x4){0.f,0.f,0.f,0.f};

    const int wrow = ot + w * 16 + li;
    const float* wr = wqkv + (size_t)wrow * CIN;

    float4 g0, g1;
    auto load_x = [&](int s) {
        const float* src = xb + (size_t)(s * 64 + sk) * NPOS + i0 + si;
        g0 = *(const float4*)src;
        g1 = *(const float4*)(src + 4);
    };
    auto store_x = [&]() {
        #pragma unroll
        for (int j = 0; j < 4; ++j) Bs[si + j][sk]     = (bf16)(&g0.x)[j];
        #pragma unroll
        for (int j = 0; j < 4; ++j) Bs[si + 4 + j][sk] = (bf16)(&g1.x)[j];
    };

    load_x(0); store_x();
    __syncthreads();

    #pragma unroll
    for (int s = 0; s < 4; ++s) {
        if (s < 3) load_x(s + 1);
        #pragma unroll
        for (int kh = 0; kh < 2; ++kh) {
            // A-frag: 8 f32 from wqkv, cvt to bf16x8
            const float* wa = wr + s * 64 + kh * 32 + quad * 8;
            float4 a0 = *(const float4*)wa;
            float4 a1 = *(const float4*)(wa + 4);
            B8 af;
            #pragma unroll
            for (int j = 0; j < 4; ++j) { af.v[j] = (bf16)(&a0.x)[j]; af.v[4 + j] = (bf16)(&a1.x)[j]; }
            #pragma unroll
            for (int n = 0; n < 2; ++n) {
                B8 bf;
                bf.h[0] = *(const bf16x4*)&Bs[n * 16 + li][kh * 32 + quad * 8];
                bf.h[1] = *(const bf16x4*)&Bs[n * 16 + li][kh * 32 + quad * 8 + 4];
                acc[n] = __builtin_amdgcn_mfma_f32_16x16x32_bf16(af.v, bf.v, acc[n], 0, 0, 0);
            }
        }
        if (s < 3) {
            __syncthreads();
            store_x();
            __syncthreads();
        }
    }

    const int obase = ot + w * 16;
    const int sect  = obase >> 7;            // 0=q 1=k 2=v
    const int oo    = obase & 127;
    const int h     = oo >> 5;
    const int dbase = (oo & 31) + quad * 4;
    const int bh    = b * NHEAD + h;

    #pragma unroll
    for (int n = 0; n < 2; ++n) {
        int i = i0 + n * 16 + li;
        f32x4 v = acc[n];
        if (sect == 0) {
            #pragma unroll
            for (int r = 0; r < 4; ++r) v[r] *= QSCALE;
        }
        if (sect <= 1) {
            bf16x4 pk;
            #pragma unroll
            for (int r = 0; r < 4; ++r) pk[r] = (bf16)v[r];
            bf16* base = (sect == 0) ? qb : kb;
            *(bf16x4*)(base + ((size_t)bh * NPOS + i) * DHEAD + dbase) = pk;
        } else {
            #pragma unroll
            for (int r = 0; r < 4; ++r)
                vtb[((size_t)bh * DHEAD + dbase + r) * NPOS + i] = (bf16)v[r];
        }
    }
}

// ---------------- Kernel 2: MFMA flash attention (R7 structure, stride-68 plds) ----------------
// R7 was the best fattn (53.5us). Single change: plds row stride 72->68 and P-frag
// reads as b64 pairs. Stride 72 = 36 banks == 4 mod 32 put all 64 lanes of each
// ds_read_b128 into an 8-bank group (8-way conflict, the constant 3.15M
// SQ_LDS_BANK_CONFLICT). Stride 68 = 34 banks == 2 mod 32 with b64 reads -> <=2-way.
__global__ __launch_bounds__(256, 4) void fattn_kernel(const bf16* __restrict__ qb,
                                                       const bf16* __restrict__ kb,
                                                       const bf16* __restrict__ vtb,
                                                       bf16* __restrict__ aop,
                                                       float* __restrict__ lpart) {
    const int id    = blockIdx.x;
    const int g     = id & 63;
    const int iblk  = id >> 6;           // 0..31
    const int bh    = g >> 3;
    const int split = g & 7;
    const int w     = threadIdx.x >> 6;
    const int lane  = threadIdx.x & 63;
    const int quad  = lane >> 4;
    const int li    = lane & 15;
    const int i0    = iblk * 128 + w * 32;
    const int j_lo  = split * 512;

    const bf16* qrow = qb + (size_t)bh * NPOS * DHEAD;
    const bf16x8 qf0 = *(const bf16x8*)(qrow + (size_t)(i0 + li) * DHEAD + quad * 8);
    const bf16x8 qf1 = *(const bf16x8*)(qrow + (size_t)(i0 + 16 + li) * DHEAD + quad * 8);
    const bf16* kbase  = kb  + (size_t)bh * NPOS * DHEAD;
    const bf16* vtbase = vtb + (size_t)bh * DHEAD * NPOS;

    bf16x8 ones;
    #pragma unroll
    for (int j = 0; j < 8; ++j) ones[j] = (bf16)1.0f;

    f32x4 o00 = {0.f,0.f,0.f,0.f}, o01 = {0.f,0.f,0.f,0.f};
    f32x4 o10 = {0.f,0.f,0.f,0.f}, o11 = {0.f,0.f,0.f,0.f};
    f32x4 l0  = {0.f,0.f,0.f,0.f}, l1  = {0.f,0.f,0.f,0.f};
    __shared__ alignas(16) bf16 plds[4][32][68];   // [wave][i][j], 17,408 B, wave-private

    const f32x4 zero = {0.f,0.f,0.f,0.f};

    auto pv_step = [&](int jp) {
        #pragma unroll
        for (int h2 = 0; h2 < 2; ++h2) {
            B8 pf0, pf1;
            pf0.h[0] = *(const bf16x4*)&plds[w][li][h2 * 32 + quad * 8];
            pf0.h[1] = *(const bf16x4*)&plds[w][li][h2 * 32 + quad * 8 + 4];
            pf1.h[0] = *(const bf16x4*)&plds[w][16 + li][h2 * 32 + quad * 8];
            pf1.h[1] = *(const bf16x4*)&plds[w][16 + li][h2 * 32 + quad * 8 + 4];
            bf16x8 v0f = *(const bf16x8*)(vtbase + (size_t)li        * NPOS + jp + h2 * 32 + quad * 8);
            bf16x8 v1f = *(const bf16x8*)(vtbase + (size_t)(16 + li) * NPOS + jp + h2 * 32 + quad * 8);
            l0  = __builtin_amdgcn_mfma_f32_16x16x32_bf16(ones, pf0.v, l0,  0, 0, 0);
            l1  = __builtin_amdgcn_mfma_f32_16x16x32_bf16(ones, pf1.v, l1,  0, 0, 0);
            o00 = __builtin_amdgcn_mfma_f32_16x16x32_bf16(v0f,  pf0.v, o00, 0, 0, 0);
            o01 = __builtin_amdgcn_mfma_f32_16x16x32_bf16(v1f,  pf0.v, o01, 0, 0, 0);
            o10 = __builtin_amdgcn_mfma_f32_16x16x32_bf16(v0f,  pf1.v, o10, 0, 0, 0);
            o11 = __builtin_amdgcn_mfma_f32_16x16x32_bf16(v1f,  pf1.v, o11, 0, 0, 0);
        }
    };

    for (int it = 0; it < 8; ++it) {
        if ((it & 3) == 0) __builtin_amdgcn_s_barrier();   // loose lockstep for L1 stream sharing
        const int j0 = j_lo + it * 64;
        // K loads + QK MFMAs for tile it
        bf16x8 kf[4];
        #pragma unroll
        for (int tt = 0; tt < 4; ++tt)
            kf[tt] = *(const bf16x8*)(kbase + (size_t)(j0 + 16 * tt + li) * DHEAD + quad * 8);
        f32x4 s0[4], s1[4];
        #pragma unroll
        for (int tt = 0; tt < 4; ++tt) {
            s0[tt] = __builtin_amdgcn_mfma_f32_16x16x32_bf16(kf[tt], qf0, zero, 0, 0, 0);
            s1[tt] = __builtin_amdgcn_mfma_f32_16x16x32_bf16(kf[tt], qf1, zero, 0, 0, 0);
        }
        // PV for tile it-1 (reads plds BEFORE this tile's writes; wave-order DS => safe)
        if (it > 0) pv_step(j_lo + (it - 1) * 64);
        // exp + pack + store tile it into plds
        #pragma unroll
        for (int tt = 0; tt < 4; ++tt) {
            bf16x4 p0, p1;
            #pragma unroll
            for (int r = 0; r < 4; ++r) {
                p0[r] = (bf16)__builtin_amdgcn_exp2f(s0[tt][r]);
                p1[r] = (bf16)__builtin_amdgcn_exp2f(s1[tt][r]);
            }
            *(bf16x4*)&plds[w][li][16 * tt + quad * 4]      = p0;
            *(bf16x4*)&plds[w][16 + li][16 * tt + quad * 4] = p1;
        }
    }
    // drain: PV for the last tile
    pv_step(j_lo + 7 * 64);

    const int b = bh >> 2, h = bh & 3;
    {
        const int i = i0 + li;
        bf16* dst = aop + (((size_t)(split * NB + b) * NPOS + i) * HID) + h * DHEAD;
        bf16x4 pk0, pk1;
        #pragma unroll
        for (int r = 0; r < 4; ++r) { pk0[r] = (bf16)o00[r]; pk1[r] = (bf16)o01[r]; }
        *(bf16x4*)(dst + quad * 4)      = pk0;
        *(bf16x4*)(dst + 16 + quad * 4) = pk1;
        if (quad == 0) lpart[((size_t)split * NBH + bh) * NPOS + i] = l0[0];
    }
    {
        const int i = i0 + 16 + li;
        bf16* dst = aop + (((size_t)(split * NB + b) * NPOS + i) * HID) + h * DHEAD;
        bf16x4 pk0, pk1;
        #pragma unroll
        for (int r = 0; r < 4; ++r) { pk0[r] = (bf16)o10[r]; pk1[r] = (bf16)o11[r]; }
        *(bf16x4*)(dst + quad * 4)      = pk0;
        *(bf16x4*)(dst + 16 + quad * 4) = pk1;
        if (quad == 0) lpart[((size_t)split * NBH + bh) * NPOS + i] = l1[0];
    }
}

// ---------------- Kernel 3: proj GEMM, fused split-combine, f32 weights ----------------
// R9: tile 32i x 64o -> grid 1024 = 4 blocks/CU (was 2). W-frags cvt'd inline from
// f32 wout. Bs stride 140 elem (b64-aligned rows, ~2-way banks for b64 frag reads).
__global__ __launch_bounds__(256) void proj_kernel(const bf16* __restrict__ aop,
                                                   const float* __restrict__ lpart,
                                                   const float* __restrict__ wout,
                                                   const float* __restrict__ bout,
                                                   float* __restrict__ y) {
    const int i0 = blockIdx.x * 32;
    const int ot = blockIdx.y * 64;
    const int b  = blockIdx.z;
    const int t  = threadIdx.x;
    const int w  = t >> 6;
    const int lane = t & 63;
    const int quad = lane >> 4;
    const int li   = lane & 15;

    __shared__ bf16 Bs[32][140];   // [i_loc][c], stride 140 elem = 280B (b64-aligned rows)

    // staging with combine: thread = (row, 16-channel chunk)
    {
        const int row = t >> 3;          // 0..31
        const int cp  = (t & 7) * 16;    // 0..112
        const int gi  = i0 + row;
        const int h   = cp >> 5;

        float lsum = 0.f;
        #pragma unroll
        for (int s = 0; s < NSPLIT; ++s)
            lsum += lpart[((size_t)s * NBH + b * NHEAD + h) * NPOS + gi];
        const float invl = __builtin_amdgcn_rcpf(lsum);

        float vals[16];
        #pragma unroll
        for (int j = 0; j < 16; ++j) vals[j] = 0.f;
        #pragma unroll
        for (int s = 0; s < NSPLIT; ++s) {
            const bf16* src = aop + (((size_t)(s * NB + b) * NPOS + gi) * HID) + cp;
            #pragma unroll
            for (int m = 0; m < 2; ++m) {
                bf16x8 u = *(const bf16x8*)(src + m * 8);
                #pragma unroll
                for (int j = 0; j < 8; ++j) vals[m * 8 + j] += (float)u[j];
            }
        }
        #pragma unroll
        for (int m = 0; m < 2; ++m) {
            B8 pk;
            #pragma unroll
            for (int j = 0; j < 8; ++j) pk.v[j] = (bf16)(vals[m * 8 + j] * invl);
            *(bf16x4*)&Bs[row][cp + m * 8]     = pk.h[0];
            *(bf16x4*)&Bs[row][cp + m * 8 + 4] = pk.h[1];
        }
    }
    __syncthreads();

    f32x4 acc[2];
    acc[0] = (f32x4){0.f,0.f,0.f,0.f};
    acc[1] = (f32x4){0.f,0.f,0.f,0.f};

    const float* wr = wout + (size_t)(ot + w * 16 + li) * HID;
    #pragma unroll
    for (int k0 = 0; k0 < HID; k0 += 32) {
        const float* wa = wr + k0 + quad * 8;
        float4 a0 = *(const float4*)wa;
        float4 a1 = *(const float4*)(wa + 4);
        B8 af;
        #pragma unroll
        for (int j = 0; j < 4; ++j) { af.v[j] = (bf16)(&a0.x)[j]; af.v[4 + j] = (bf16)(&a1.x)[j]; }
        #pragma unroll
        for (int n = 0; n < 2; ++n) {
            B8 bf;
            bf.h[0] = *(const bf16x4*)&Bs[n * 16 + li][k0 + quad * 8];
            bf.h[1] = *(const bf16x4*)&Bs[n * 16 + li][k0 + quad * 8 + 4];
            acc[n] = __builtin_amdgcn_mfma_f32_16x16x32_bf16(af.v, bf.v, acc[n], 0, 0, 0);
        }
    }

    float bias[4];
    #pragma unroll
    for (int r = 0; r < 4; ++r) bias[r] = bout[ot + w * 16 + quad * 4 + r];
    float* yb = y + (size_t)b * CIN * NPOS;
    #pragma unroll
    for (int n = 0; n < 2; ++n) {
        int i = i0 + n * 16 + li;
        #pragma unroll
        for (int r = 0; r < 4; ++r)
            yb[(size_t)(ot + w * 16 + quad * 4 + r) * NPOS + i] = acc[n][r] + bias[r];
    }
}

extern "C" void kernel_launch(void* const* d_in, const int* in_sizes, int n_in,
                              void* d_out, int out_size, void* d_ws, size_t ws_size,
                              hipStream_t stream) {
    const float* x    = (const float*)d_in[0];
    const float* wqkv = (const float*)d_in[1];
    const float* wout = (const float*)d_in[2];
    const float* bout = (const float*)d_in[3];
    float* y = (float*)d_out;
    char* ws = (char*)d_ws;

    bf16*  qb  = (bf16*)(ws + QB_OFF);
    bf16*  kb  = (bf16*)(ws + KB_OFF);
    bf16*  vtb = (bf16*)(ws + VT_OFF);
    float* lp  = (float*)(ws + LP_OFF);
    bf16*  aop = (bf16*)(ws + AOP_OFF);

    qkv_kernel<<<dim3(128, 6, 2), 256, 0, stream>>>(x, wqkv, qb, kb, vtb);
    fattn_kernel<<<dim3(2048), 256, 0, stream>>>(qb, kb, vtb, aop, lp);
    proj_kernel<<<dim3(128, 4, 2), 256, 0, stream>>>(aop, lp, wout, bout, y);
}

// Round 5
// 141.178 us; speedup vs baseline: 1.0137x; 1.0124x over previous
//
#include <hip/hip_runtime.h>
#include <hip/hip_bf16.h>
#include <math.h>

#define NB 2
#define CIN 256
#define NPOS 4096          // 64*64
#define HID 128
#define NHEAD 4
#define DHEAD 32
#define NBH 8
#define NSPLIT 8
#define QSCALE 0.2550348676144781f   // 32^-0.5 * log2(e), applied in qkv epilogue

typedef __bf16 bf16;
typedef __attribute__((ext_vector_type(8))) __bf16 bf16x8;
typedef __attribute__((ext_vector_type(4))) __bf16 bf16x4;
typedef __attribute__((ext_vector_type(4))) float f32x4;

union B8 { bf16x8 v; bf16x4 h[2]; };

// ws layout (byte offsets), total 24,117,248 B:
#define QB_OFF  0u            // qb  bf16 [8][4096][32]     2 MB
#define KB_OFF  2097152u      // kb  bf16 [8][4096][32]     2 MB
#define VT_OFF  4194304u      // vtb bf16 [8][32][4096]     2 MB  (V transposed)
#define LP_OFF  6291456u      // lp  f32  [8][8][4096]      1 MB
#define AOP_OFF 7340032u      // aop bf16 [8][2][4096][128] 16 MB

// ---------------- Kernel 1: qkv GEMM — x read EXACTLY once ----------------
// R10: R9's qkv re-read x once per ot-tile (grid.y=6 -> 48 MB L3/HBM traffic, the
// dominant non-fattn cost). Now: one block per (32-i-tile, b) = 256 blocks x 512 thr
// (8 waves = 2 waves/SIMD). Block stages its full 32x256 x-tile once (8 MB total x
// traffic) and computes ALL 384 outputs. W streams from L2 (384 KB resident, ~96 MB
// aggregate). Per wave: 3 o-subtiles x 2 i-subtiles x 8 k-steps = 48 MFMAs, 6 acc.
__global__ __launch_bounds__(512) void qkv_kernel(const float* __restrict__ x,
                                                  const float* __restrict__ wqkv,
                                                  bf16* __restrict__ qb,
                                                  bf16* __restrict__ kb,
                                                  bf16* __restrict__ vtb) {
    const int i0 = blockIdx.x * 32;
    const int b  = blockIdx.y;
    const int t  = threadIdx.x;
    const int w  = t >> 6;          // 0..7
    const int lane = t & 63;
    const int quad = lane >> 4;
    const int li   = lane & 15;

    __shared__ bf16 Bs[32][260];    // [i_loc][k]; stride 260 elem = 130 banks == 2 mod 32

    // ---- stage x-tile: 32 i x 256 c, coalesced float4 along i ----
    {
        const int il = (t & 7) * 4;           // i chunk of 4
        #pragma unroll
        for (int u = 0; u < 4; ++u) {
            const int c = (t >> 3) + u * 64;  // 0..255
            float4 v = *(const float4*)(x + ((size_t)b * CIN + c) * NPOS + i0 + il);
            Bs[il    ][c] = (bf16)v.x;
            Bs[il + 1][c] = (bf16)v.y;
            Bs[il + 2][c] = (bf16)v.z;
            Bs[il + 3][c] = (bf16)v.w;
        }
    }
    __syncthreads();

    f32x4 acc[2][3];
    #pragma unroll
    for (int n = 0; n < 2; ++n)
        #pragma unroll
        for (int m = 0; m < 3; ++m) acc[n][m] = (f32x4){0.f,0.f,0.f,0.f};

    #pragma unroll
    for (int k0 = 0; k0 < CIN; k0 += 32) {
        B8 bfr[2];
        #pragma unroll
        for (int n = 0; n < 2; ++n) {
            bfr[n].h[0] = *(const bf16x4*)&Bs[n * 16 + li][k0 + quad * 8];
            bfr[n].h[1] = *(const bf16x4*)&Bs[n * 16 + li][k0 + quad * 8 + 4];
        }
        #pragma unroll
        for (int m = 0; m < 3; ++m) {
            const int orow = w * 48 + m * 16 + li;
            const float* wa = wqkv + (size_t)orow * CIN + k0 + quad * 8;
            float4 a0 = *(const float4*)wa;
            float4 a1 = *(const float4*)(wa + 4);
            B8 af;
            #pragma unroll
            for (int j = 0; j < 4; ++j) { af.v[j] = (bf16)(&a0.x)[j]; af.v[4 + j] = (bf16)(&a1.x)[j]; }
            #pragma unroll
            for (int n = 0; n < 2; ++n)
                acc[n][m] = __builtin_amdgcn_mfma_f32_16x16x32_bf16(af.v, bfr[n].v, acc[n][m], 0, 0, 0);
        }
    }

    #pragma unroll
    for (int m = 0; m < 3; ++m) {
        const int obase = w * 48 + m * 16;
        const int sect  = obase >> 7;            // 0=q 1=k 2=v
        const int oo    = obase & 127;
        const int h     = oo >> 5;
        const int dbase = (oo & 31) + quad * 4;
        const int bh    = b * NHEAD + h;
        #pragma unroll
        for (int n = 0; n < 2; ++n) {
            int i = i0 + n * 16 + li;
            f32x4 v = acc[n][m];
            if (sect == 0) {
                #pragma unroll
                for (int r = 0; r < 4; ++r) v[r] *= QSCALE;
            }
            if (sect <= 1) {
                bf16x4 pk;
                #pragma unroll
                for (int r = 0; r < 4; ++r) pk[r] = (bf16)v[r];
                bf16* base = (sect == 0) ? qb : kb;
                *(bf16x4*)(base + ((size_t)bh * NPOS + i) * DHEAD + dbase) = pk;
            } else {
                #pragma unroll
                for (int r = 0; r < 4; ++r)
                    vtb[((size_t)bh * DHEAD + dbase + r) * NPOS + i] = (bf16)v[r];
            }
        }
    }
}

// ---------------- Kernel 2: MFMA flash attention (unchanged from R9) ----------------
__global__ __launch_bounds__(256, 4) void fattn_kernel(const bf16* __restrict__ qb,
                                                       const bf16* __restrict__ kb,
                                                       const bf16* __restrict__ vtb,
                                                       bf16* __restrict__ aop,
                                                       float* __restrict__ lpart) {
    const int id    = blockIdx.x;
    const int g     = id & 63;
    const int iblk  = id >> 6;           // 0..31
    const int bh    = g >> 3;
    const int split = g & 7;
    const int w     = threadIdx.x >> 6;
    const int lane  = threadIdx.x & 63;
    const int quad  = lane >> 4;
    const int li    = lane & 15;
    const int i0    = iblk * 128 + w * 32;
    const int j_lo  = split * 512;

    const bf16* qrow = qb + (size_t)bh * NPOS * DHEAD;
    const bf16x8 qf0 = *(const bf16x8*)(qrow + (size_t)(i0 + li) * DHEAD + quad * 8);
    const bf16x8 qf1 = *(const bf16x8*)(qrow + (size_t)(i0 + 16 + li) * DHEAD + quad * 8);
    const bf16* kbase  = kb  + (size_t)bh * NPOS * DHEAD;
    const bf16* vtbase = vtb + (size_t)bh * DHEAD * NPOS;

    bf16x8 ones;
    #pragma unroll
    for (int j = 0; j < 8; ++j) ones[j] = (bf16)1.0f;

    f32x4 o00 = {0.f,0.f,0.f,0.f}, o01 = {0.f,0.f,0.f,0.f};
    f32x4 o10 = {0.f,0.f,0.f,0.f}, o11 = {0.f,0.f,0.f,0.f};
    f32x4 l0  = {0.f,0.f,0.f,0.f}, l1  = {0.f,0.f,0.f,0.f};
    __shared__ alignas(16) bf16 plds[4][32][68];   // [wave][i][j], 17,408 B, wave-private

    const f32x4 zero = {0.f,0.f,0.f,0.f};

    auto pv_step = [&](int jp) {
        #pragma unroll
        for (int h2 = 0; h2 < 2; ++h2) {
            B8 pf0, pf1;
            pf0.h[0] = *(const bf16x4*)&plds[w][li][h2 * 32 + quad * 8];
            pf0.h[1] = *(const bf16x4*)&plds[w][li][h2 * 32 + quad * 8 + 4];
            pf1.h[0] = *(const bf16x4*)&plds[w][16 + li][h2 * 32 + quad * 8];
            pf1.h[1] = *(const bf16x4*)&plds[w][16 + li][h2 * 32 + quad * 8 + 4];
            bf16x8 v0f = *(const bf16x8*)(vtbase + (size_t)li        * NPOS + jp + h2 * 32 + quad * 8);
            bf16x8 v1f = *(const bf16x8*)(vtbase + (size_t)(16 + li) * NPOS + jp + h2 * 32 + quad * 8);
            l0  = __builtin_amdgcn_mfma_f32_16x16x32_bf16(ones, pf0.v, l0,  0, 0, 0);
            l1  = __builtin_amdgcn_mfma_f32_16x16x32_bf16(ones, pf1.v, l1,  0, 0, 0);
            o00 = __builtin_amdgcn_mfma_f32_16x16x32_bf16(v0f,  pf0.v, o00, 0, 0, 0);
            o01 = __builtin_amdgcn_mfma_f32_16x16x32_bf16(v1f,  pf0.v, o01, 0, 0, 0);
            o10 = __builtin_amdgcn_mfma_f32_16x16x32_bf16(v0f,  pf1.v, o10, 0, 0, 0);
            o11 = __builtin_amdgcn_mfma_f32_16x16x32_bf16(v1f,  pf1.v, o11, 0, 0, 0);
        }
    };

    for (int it = 0; it < 8; ++it) {
        if ((it & 3) == 0) __builtin_amdgcn_s_barrier();   // loose lockstep for L1 stream sharing
        const int j0 = j_lo + it * 64;
        bf16x8 kf[4];
        #pragma unroll
        for (int tt = 0; tt < 4; ++tt)
            kf[tt] = *(const bf16x8*)(kbase + (size_t)(j0 + 16 * tt + li) * DHEAD + quad * 8);
        f32x4 s0[4], s1[4];
        #pragma unroll
        for (int tt = 0; tt < 4; ++tt) {
            s0[tt] = __builtin_amdgcn_mfma_f32_16x16x32_bf16(kf[tt], qf0, zero, 0, 0, 0);
            s1[tt] = __builtin_amdgcn_mfma_f32_16x16x32_bf16(kf[tt], qf1, zero, 0, 0, 0);
        }
        if (it > 0) pv_step(j_lo + (it - 1) * 64);
        #pragma unroll
        for (int tt = 0; tt < 4; ++tt) {
            bf16x4 p0, p1;
            #pragma unroll
            for (int r = 0; r < 4; ++r) {
                p0[r] = (bf16)__builtin_amdgcn_exp2f(s0[tt][r]);
                p1[r] = (bf16)__builtin_amdgcn_exp2f(s1[tt][r]);
            }
            *(bf16x4*)&plds[w][li][16 * tt + quad * 4]      = p0;
            *(bf16x4*)&plds[w][16 + li][16 * tt + quad * 4] = p1;
        }
    }
    pv_step(j_lo + 7 * 64);

    const int b = bh >> 2, h = bh & 3;
    {
        const int i = i0 + li;
        bf16* dst = aop + (((size_t)(split * NB + b) * NPOS + i) * HID) + h * DHEAD;
        bf16x4 pk0, pk1;
        #pragma unroll
        for (int r = 0; r < 4; ++r) { pk0[r] = (bf16)o00[r]; pk1[r] = (bf16)o01[r]; }
        *(bf16x4*)(dst + quad * 4)      = pk0;
        *(bf16x4*)(dst + 16 + quad * 4) = pk1;
        if (quad == 0) lpart[((size_t)split * NBH + bh) * NPOS + i] = l0[0];
    }
    {
        const int i = i0 + 16 + li;
        bf16* dst = aop + (((size_t)(split * NB + b) * NPOS + i) * HID) + h * DHEAD;
        bf16x4 pk0, pk1;
        #pragma unroll
        for (int r = 0; r < 4; ++r) { pk0[r] = (bf16)o10[r]; pk1[r] = (bf16)o11[r]; }
        *(bf16x4*)(dst + quad * 4)      = pk0;
        *(bf16x4*)(dst + 16 + quad * 4) = pk1;
        if (quad == 0) lpart[((size_t)split * NBH + bh) * NPOS + i] = l1[0];
    }
}

// ---------------- Kernel 3: proj GEMM, fused split-combine, f32 weights (unchanged) ----------------
__global__ __launch_bounds__(256) void proj_kernel(const bf16* __restrict__ aop,
                                                   const float* __restrict__ lpart,
                                                   const float* __restrict__ wout,
                                                   const float* __restrict__ bout,
                                                   float* __restrict__ y) {
    const int i0 = blockIdx.x * 32;
    const int ot = blockIdx.y * 64;
    const int b  = blockIdx.z;
    const int t  = threadIdx.x;
    const int w  = t >> 6;
    const int lane = t & 63;
    const int quad = lane >> 4;
    const int li   = lane & 15;

    __shared__ bf16 Bs[32][140];   // [i_loc][c]

    {
        const int row = t >> 3;          // 0..31
        const int cp  = (t & 7) * 16;    // 0..112
        const int gi  = i0 + row;
        const int h   = cp >> 5;

        float lsum = 0.f;
        #pragma unroll
        for (int s = 0; s < NSPLIT; ++s)
            lsum += lpart[((size_t)s * NBH + b * NHEAD + h) * NPOS + gi];
        const float invl = __builtin_amdgcn_rcpf(lsum);

        float vals[16];
        #pragma unroll
        for (int j = 0; j < 16; ++j) vals[j] = 0.f;
        #pragma unroll
        for (int s = 0; s < NSPLIT; ++s) {
            const bf16* src = aop + (((size_t)(s * NB + b) * NPOS + gi) * HID) + cp;
            #pragma unroll
            for (int m = 0; m < 2; ++m) {
                bf16x8 u = *(const bf16x8*)(src + m * 8);
                #pragma unroll
                for (int j = 0; j < 8; ++j) vals[m * 8 + j] += (float)u[j];
            }
        }
        #pragma unroll
        for (int m = 0; m < 2; ++m) {
            B8 pk;
            #pragma unroll
            for (int j = 0; j < 8; ++j) pk.v[j] = (bf16)(vals[m * 8 + j] * invl);
            *(bf16x4*)&Bs[row][cp + m * 8]     = pk.h[0];
            *(bf16x4*)&Bs[row][cp + m * 8 + 4] = pk.h[1];
        }
    }
    __syncthreads();

    f32x4 acc[2];
    acc[0] = (f32x4){0.f,0.f,0.f,0.f};
    acc[1] = (f32x4){0.f,0.f,0.f,0.f};

    const float* wr = wout + (size_t)(ot + w * 16 + li) * HID;
    #pragma unroll
    for (int k0 = 0; k0 < HID; k0 += 32) {
        const float* wa = wr + k0 + quad * 8;
        float4 a0 = *(const float4*)wa;
        float4 a1 = *(const float4*)(wa + 4);
        B8 af;
        #pragma unroll
        for (int j = 0; j < 4; ++j) { af.v[j] = (bf16)(&a0.x)[j]; af.v[4 + j] = (bf16)(&a1.x)[j]; }
        #pragma unroll
        for (int n = 0; n < 2; ++n) {
            B8 bf;
            bf.h[0] = *(const bf16x4*)&Bs[n * 16 + li][k0 + quad * 8];
            bf.h[1] = *(const bf16x4*)&Bs[n * 16 + li][k0 + quad * 8 + 4];
            acc[n] = __builtin_amdgcn_mfma_f32_16x16x32_bf16(af.v, bf.v, acc[n], 0, 0, 0);
        }
    }

    float bias[4];
    #pragma unroll
    for (int r = 0; r < 4; ++r) bias[r] = bout[ot + w * 16 + quad * 4 + r];
    float* yb = y + (size_t)b * CIN * NPOS;
    #pragma unroll
    for (int n = 0; n < 2; ++n) {
        int i = i0 + n * 16 + li;
        #pragma unroll
        for (int r = 0; r < 4; ++r)
            yb[(size_t)(ot + w * 16 + quad * 4 + r) * NPOS + i] = acc[n][r] + bias[r];
    }
}

extern "C" void kernel_launch(void* const* d_in, const int* in_sizes, int n_in,
                              void* d_out, int out_size, void* d_ws, size_t ws_size,
                              hipStream_t stream) {
    const float* x    = (const float*)d_in[0];
    const float* wqkv = (const float*)d_in[1];
    const float* wout = (const float*)d_in[2];
    const float* bout = (const float*)d_in[3];
    float* y = (float*)d_out;
    char* ws = (char*)d_ws;

    bf16*  qb  = (bf16*)(ws + QB_OFF);
    bf16*  kb  = (bf16*)(ws + KB_OFF);
    bf16*  vtb = (bf16*)(ws + VT_OFF);
    float* lp  = (float*)(ws + LP_OFF);
    bf16*  aop = (bf16*)(ws + AOP_OFF);

    qkv_kernel<<<dim3(128, 2), 512, 0, stream>>>(x, wqkv, qb, kb, vtb);
    fattn_kernel<<<dim3(2048), 256, 0, stream>>>(qb, kb, vtb, aop, lp);
    proj_kernel<<<dim3(128, 4, 2), 256, 0, stream>>>(aop, lp, wout, bout, y);
}

// Round 6
// 129.177 us; speedup vs baseline: 1.1078x; 1.0929x over previous
//
#include <hip/hip_runtime.h>
#include <hip/hip_bf16.h>
#include <math.h>

#define NB 2
#define CIN 256
#define NPOS 4096          // 64*64
#define HID 128
#define NHEAD 4
#define DHEAD 32
#define NBH 8
#define NSPLIT 4
#define QSCALE 0.2550348676144781f   // 32^-0.5 * log2(e), folded into W_q

typedef __bf16 bf16;
typedef __attribute__((ext_vector_type(8))) __bf16 bf16x8;
typedef __attribute__((ext_vector_type(4))) __bf16 bf16x4;
typedef __attribute__((ext_vector_type(4))) float f32x4;

union B8 { bf16x8 v; bf16x4 h[2]; };

// ws layout (byte offsets), total 19,660,800 B (R0 layout, best-measured):
#define XT_OFF  0u            // xt  bf16 [2][4096][256]   4 MB
#define QB_OFF  4194304u      // qb  bf16 [8][4096][32]    2 MB  (W_q pre-scaled by QSCALE)
#define KB_OFF  6291456u      // kb  bf16 [8][4096][32]    2 MB
#define VT_OFF  8388608u      // vtb bf16 [8][32][4096]    2 MB  (V transposed)
#define AOP_OFF 10485760u     // aop bf16 [4][2][4096][128] 8 MB (partial O, [split][b][i][c])
#define LP_OFF  18874368u     // lp  f32  [4][8][4096]     512 KB
#define WB_OFF  19398656u     // wb  bf16 [384][256]       192 KB
#define WOB_OFF 19595264u     // wob bf16 [256][128]       64 KB

// ---------------- Kernel 0: prep — transpose x to bf16 [b][i][c]; cast weights ----------------
__global__ __launch_bounds__(256) void prep_kernel(const float* __restrict__ x,
                                                   const float* __restrict__ wqkv,
                                                   const float* __restrict__ wout,
                                                   bf16* __restrict__ xt,
                                                   bf16* __restrict__ wb,
                                                   bf16* __restrict__ wob) {
    const int t = threadIdx.x;
    if (blockIdx.y == 4) {
        int tid = blockIdx.x * 256 + t;           // 0..16383
        if (blockIdx.z == 0) {
            #pragma unroll
            for (int u = 0; u < 6; ++u) {
                int idx = tid * 6 + u;            // 98304 = 384*256 exactly
                float v = wqkv[idx];
                if (idx < 32768) v *= QSCALE;     // rows 0..127 = W_q
                wb[idx] = (bf16)v;
            }
        } else {
            wob[tid * 2]     = (bf16)wout[tid * 2];     // 32768 = 256*128
            wob[tid * 2 + 1] = (bf16)wout[tid * 2 + 1];
        }
        return;
    }
    const int b  = blockIdx.z;
    const int c0 = blockIdx.y * 64;
    const int i0 = blockIdx.x * 64;
    __shared__ float Ts[64][65];
    const float* xb = x + (size_t)b * CIN * NPOS;
    #pragma unroll
    for (int u = 0; u < 4; ++u) {
        int c = (t >> 4) + u * 16;
        int i = (t & 15) * 4;
        float4 v = *(const float4*)(xb + (size_t)(c0 + c) * NPOS + i0 + i);
        Ts[c][i] = v.x; Ts[c][i + 1] = v.y; Ts[c][i + 2] = v.z; Ts[c][i + 3] = v.w;
    }
    __syncthreads();
    int i  = t & 63;
    int cc = (t >> 6) * 16;
    B8 o0, o1;
    #pragma unroll
    for (int j = 0; j < 8; ++j) {
        o0.v[j] = (bf16)Ts[cc + j][i];
        o1.v[j] = (bf16)Ts[cc + 8 + j][i];
    }
    bf16* dst = xt + ((size_t)b * NPOS + i0 + i) * CIN + c0 + cc;
    *(bf16x8*)dst       = o0.v;
    *(bf16x8*)(dst + 8) = o1.v;
}

// ---------------- Kernel 1: qkv MFMA GEMM (R0 verbatim) ----------------
__global__ __launch_bounds__(256) void qkv_kernel(const bf16* __restrict__ xt,
                                                  const bf16* __restrict__ wb,
                                                  bf16* __restrict__ qb,
                                                  bf16* __restrict__ kb,
                                                  bf16* __restrict__ vtb) {
    const int i0 = blockIdx.x * 64;
    const int ot = blockIdx.y * 64;
    const int b  = blockIdx.z;
    const int t  = threadIdx.x;
    const int w  = t >> 6;
    const int lane = t & 63;
    const int quad = lane >> 4;
    const int li   = lane & 15;

    __shared__ bf16 Bs[64][36];   // [i_loc][k]

    f32x4 acc[4];
    #pragma unroll
    for (int n = 0; n < 4; ++n) acc[n] = (f32x4){0.f, 0.f, 0.f, 0.f};

    const bf16* xrow = xt + ((size_t)b * NPOS + i0) * CIN;
    const int si = t >> 2;            // 0..63
    const int sk = (t & 3) * 8;       // 0,8,16,24

    for (int k0 = 0; k0 < CIN; k0 += 32) {
        __syncthreads();
        B8 g0;
        g0.v = *(const bf16x8*)(xrow + (size_t)si * CIN + k0 + sk);
        *(bf16x4*)&Bs[si][sk]     = g0.h[0];
        *(bf16x4*)&Bs[si][sk + 4] = g0.h[1];
        __syncthreads();
        bf16x8 afrag = *(const bf16x8*)(wb + (size_t)(ot + w * 16 + li) * CIN + k0 + quad * 8);
        #pragma unroll
        for (int n = 0; n < 4; ++n) {
            B8 bf;
            bf.h[0] = *(const bf16x4*)&Bs[n * 16 + li][quad * 8];
            bf.h[1] = *(const bf16x4*)&Bs[n * 16 + li][quad * 8 + 4];
            acc[n] = __builtin_amdgcn_mfma_f32_16x16x32_bf16(afrag, bf.v, acc[n], 0, 0, 0);
        }
    }

    const int obase = ot + w * 16;
    const int sect  = obase >> 7;            // 0=q 1=k 2=v
    const int oo    = obase & 127;
    const int h     = oo >> 5;
    const int dbase = (oo & 31) + quad * 4;
    const int bh    = b * NHEAD + h;

    #pragma unroll
    for (int n = 0; n < 4; ++n) {
        int i = i0 + n * 16 + li;
        f32x4 v = acc[n];
        if (sect <= 1) {
            bf16x4 pk;
            #pragma unroll
            for (int r = 0; r < 4; ++r) pk[r] = (bf16)v[r];
            bf16* base = (sect == 0) ? qb : kb;
            *(bf16x4*)(base + ((size_t)bh * NPOS + i) * DHEAD + dbase) = pk;
        } else {
            #pragma unroll
            for (int r = 0; r < 4; ++r)
                vtb[((size_t)bh * DHEAD + dbase + r) * NPOS + i] = (bf16)v[r];
        }
    }
}

// ---------------- Kernel 2: MFMA flash attention, NSPLIT=4 (R0 structure) ----------------
// R11: R0's fattn (best total config) with the three individually-proven-neutral
// cleanups from R7-R10: single-buffer plds (36->17.4 KB; wave-private + wave-order DS
// => read(t-1)-before-write(t) is hazard-free), stride-68 rows (bank conflicts
// 3.15M -> 0, measured R9/R10), raw v_exp_f32. Grid 1024 = 4 blocks/CU, one clean
// residency round at the register-forced 4 waves/SIMD.
__global__ __launch_bounds__(256, 4) void fattn_kernel(const bf16* __restrict__ qb,
                                                       const bf16* __restrict__ kb,
                                                       const bf16* __restrict__ vtb,
                                                       bf16* __restrict__ aop,
                                                       float* __restrict__ lpart) {
    const int id    = blockIdx.x;
    const int g     = id & 31;
    const int iblk  = id >> 5;           // 0..31
    const int bh    = g >> 2;
    const int split = g & 3;
    const int w     = threadIdx.x >> 6;
    const int lane  = threadIdx.x & 63;
    const int quad  = lane >> 4;
    const int li    = lane & 15;
    const int i0    = iblk * 128 + w * 32;
    const int j_lo  = split * 1024;

    const bf16* qrow = qb + (size_t)bh * NPOS * DHEAD;
    const bf16x8 qf0 = *(const bf16x8*)(qrow + (size_t)(i0 + li) * DHEAD + quad * 8);
    const bf16x8 qf1 = *(const bf16x8*)(qrow + (size_t)(i0 + 16 + li) * DHEAD + quad * 8);
    const bf16* kbase  = kb  + (size_t)bh * NPOS * DHEAD;
    const bf16* vtbase = vtb + (size_t)bh * DHEAD * NPOS;

    bf16x8 ones;
    #pragma unroll
    for (int j = 0; j < 8; ++j) ones[j] = (bf16)1.0f;

    f32x4 o00 = {0.f,0.f,0.f,0.f}, o01 = {0.f,0.f,0.f,0.f};
    f32x4 o10 = {0.f,0.f,0.f,0.f}, o11 = {0.f,0.f,0.f,0.f};
    f32x4 l0  = {0.f,0.f,0.f,0.f}, l1  = {0.f,0.f,0.f,0.f};
    __shared__ alignas(16) bf16 plds[4][32][68];   // [wave][i][j], 17,408 B, wave-private

    const f32x4 zero = {0.f,0.f,0.f,0.f};

    auto pv_step = [&](int jp) {
        #pragma unroll
        for (int h2 = 0; h2 < 2; ++h2) {
            B8 pf0, pf1;
            pf0.h[0] = *(const bf16x4*)&plds[w][li][h2 * 32 + quad * 8];
            pf0.h[1] = *(const bf16x4*)&plds[w][li][h2 * 32 + quad * 8 + 4];
            pf1.h[0] = *(const bf16x4*)&plds[w][16 + li][h2 * 32 + quad * 8];
            pf1.h[1] = *(const bf16x4*)&plds[w][16 + li][h2 * 32 + quad * 8 + 4];
            bf16x8 v0f = *(const bf16x8*)(vtbase + (size_t)li        * NPOS + jp + h2 * 32 + quad * 8);
            bf16x8 v1f = *(const bf16x8*)(vtbase + (size_t)(16 + li) * NPOS + jp + h2 * 32 + quad * 8);
            l0  = __builtin_amdgcn_mfma_f32_16x16x32_bf16(ones, pf0.v, l0,  0, 0, 0);
            l1  = __builtin_amdgcn_mfma_f32_16x16x32_bf16(ones, pf1.v, l1,  0, 0, 0);
            o00 = __builtin_amdgcn_mfma_f32_16x16x32_bf16(v0f,  pf0.v, o00, 0, 0, 0);
            o01 = __builtin_amdgcn_mfma_f32_16x16x32_bf16(v1f,  pf0.v, o01, 0, 0, 0);
            o10 = __builtin_amdgcn_mfma_f32_16x16x32_bf16(v0f,  pf1.v, o10, 0, 0, 0);
            o11 = __builtin_amdgcn_mfma_f32_16x16x32_bf16(v1f,  pf1.v, o11, 0, 0, 0);
        }
    };

    for (int it = 0; it < 16; ++it) {
        if ((it & 3) == 0) __builtin_amdgcn_s_barrier();   // loose lockstep for L1 stream sharing
        const int j0 = j_lo + it * 64;
        // K loads + QK MFMAs for tile it
        bf16x8 kf[4];
        #pragma unroll
        for (int tt = 0; tt < 4; ++tt)
            kf[tt] = *(const bf16x8*)(kbase + (size_t)(j0 + 16 * tt + li) * DHEAD + quad * 8);
        f32x4 s0[4], s1[4];
        #pragma unroll
        for (int tt = 0; tt < 4; ++tt) {
            s0[tt] = __builtin_amdgcn_mfma_f32_16x16x32_bf16(kf[tt], qf0, zero, 0, 0, 0);
            s1[tt] = __builtin_amdgcn_mfma_f32_16x16x32_bf16(kf[tt], qf1, zero, 0, 0, 0);
        }
        // PV for tile it-1 (reads plds BEFORE this tile's writes; wave-order DS => safe)
        if (it > 0) pv_step(j_lo + (it - 1) * 64);
        // exp + pack + store tile it into plds
        #pragma unroll
        for (int tt = 0; tt < 4; ++tt) {
            bf16x4 p0, p1;
            #pragma unroll
            for (int r = 0; r < 4; ++r) {
                p0[r] = (bf16)__builtin_amdgcn_exp2f(s0[tt][r]);
                p1[r] = (bf16)__builtin_amdgcn_exp2f(s1[tt][r]);
            }
            *(bf16x4*)&plds[w][li][16 * tt + quad * 4]      = p0;
            *(bf16x4*)&plds[w][16 + li][16 * tt + quad * 4] = p1;
        }
    }
    // drain: PV for the last tile
    pv_step(j_lo + 15 * 64);

    const int b = bh >> 2, h = bh & 3;
    {
        const int i = i0 + li;
        bf16* dst = aop + (((size_t)(split * NB + b) * NPOS + i) * HID) + h * DHEAD;
        bf16x4 pk0, pk1;
        #pragma unroll
        for (int r = 0; r < 4; ++r) { pk0[r] = (bf16)o00[r]; pk1[r] = (bf16)o01[r]; }
        *(bf16x4*)(dst + quad * 4)      = pk0;
        *(bf16x4*)(dst + 16 + quad * 4) = pk1;
        if (quad == 0) lpart[((size_t)split * NBH + bh) * NPOS + i] = l0[0];
    }
    {
        const int i = i0 + 16 + li;
        bf16* dst = aop + (((size_t)(split * NB + b) * NPOS + i) * HID) + h * DHEAD;
        bf16x4 pk0, pk1;
        #pragma unroll
        for (int r = 0; r < 4; ++r) { pk0[r] = (bf16)o10[r]; pk1[r] = (bf16)o11[r]; }
        *(bf16x4*)(dst + quad * 4)      = pk0;
        *(bf16x4*)(dst + 16 + quad * 4) = pk1;
        if (quad == 0) lpart[((size_t)split * NBH + bh) * NPOS + i] = l1[0];
    }
}

// ---------------- Kernel 3: proj GEMM with fused split-combine (R0 verbatim, NSPLIT=4) ----------------
__global__ __launch_bounds__(256) void proj_kernel(const bf16* __restrict__ aop,
                                                   const float* __restrict__ lpart,
                                                   const bf16* __restrict__ wob,
                                                   const float* __restrict__ bout,
                                                   float* __restrict__ y) {
    const int i0 = blockIdx.x * 64;
    const int ot = blockIdx.y * 64;
    const int b  = blockIdx.z;
    const int t  = threadIdx.x;
    const int w  = t >> 6;
    const int lane = t & 63;
    const int quad = lane >> 4;
    const int li   = lane & 15;

    __shared__ bf16 Bs[64][132];   // [i_loc][c]

    // staging with combine: thread = (row, 32-channel chunk)
    {
        const int row = t >> 2;          // 0..63
        const int cp  = (t & 3) * 32;    // 0,32,64,96 (one head each)
        const int gi  = i0 + row;
        const int h   = cp >> 5;

        float lsum = 0.f;
        #pragma unroll
        for (int s = 0; s < NSPLIT; ++s)
            lsum += lpart[((size_t)s * NBH + b * NHEAD + h) * NPOS + gi];
        const float invl = __builtin_amdgcn_rcpf(lsum);

        float vals[32];
        #pragma unroll
        for (int j = 0; j < 32; ++j) vals[j] = 0.f;
        #pragma unroll
        for (int s = 0; s < NSPLIT; ++s) {
            const bf16* src = aop + (((size_t)(s * NB + b) * NPOS + gi) * HID) + cp;
            #pragma unroll
            for (int m = 0; m < 4; ++m) {
                bf16x8 u = *(const bf16x8*)(src + m * 8);
                #pragma unroll
                for (int j = 0; j < 8; ++j) vals[m * 8 + j] += (float)u[j];
            }
        }
        #pragma unroll
        for (int m = 0; m < 4; ++m) {
            B8 pk;
            #pragma unroll
            for (int j = 0; j < 8; ++j) pk.v[j] = (bf16)(vals[m * 8 + j] * invl);
            *(bf16x8*)&Bs[row][cp + m * 8] = pk.v;
        }
    }
    __syncthreads();

    f32x4 acc[4];
    #pragma unroll
    for (int n = 0; n < 4; ++n) acc[n] = (f32x4){0.f, 0.f, 0.f, 0.f};

    #pragma unroll
    for (int k0 = 0; k0 < HID; k0 += 32) {
        bf16x8 afrag = *(const bf16x8*)(wob + (size_t)(ot + w * 16 + li) * HID + k0 + quad * 8);
        #pragma unroll
        for (int n = 0; n < 4; ++n) {
            B8 bf;
            bf.h[0] = *(const bf16x4*)&Bs[n * 16 + li][k0 + quad * 8];
            bf.h[1] = *(const bf16x4*)&Bs[n * 16 + li][k0 + quad * 8 + 4];
            acc[n] = __builtin_amdgcn_mfma_f32_16x16x32_bf16(afrag, bf.v, acc[n], 0, 0, 0);
        }
    }

    float bias[4];
    #pragma unroll
    for (int r = 0; r < 4; ++r) bias[r] = bout[ot + w * 16 + quad * 4 + r];
    float* yb = y + (size_t)b * CIN * NPOS;
    #pragma unroll
    for (int n = 0; n < 4; ++n) {
        int i = i0 + n * 16 + li;
        #pragma unroll
        for (int r = 0; r < 4; ++r)
            yb[(size_t)(ot + w * 16 + quad * 4 + r) * NPOS + i] = acc[n][r] + bias[r];
    }
}

extern "C" void kernel_launch(void* const* d_in, const int* in_sizes, int n_in,
                              void* d_out, int out_size, void* d_ws, size_t ws_size,
                              hipStream_t stream) {
    const float* x    = (const float*)d_in[0];
    const float* wqkv = (const float*)d_in[1];
    const float* wout = (const float*)d_in[2];
    const float* bout = (const float*)d_in[3];
    float* y = (float*)d_out;
    char* ws = (char*)d_ws;

    bf16*  xt  = (bf16*)(ws + XT_OFF);
    bf16*  qb  = (bf16*)(ws + QB_OFF);
    bf16*  kb  = (bf16*)(ws + KB_OFF);
    bf16*  vtb = (bf16*)(ws + VT_OFF);
    bf16*  aop = (bf16*)(ws + AOP_OFF);
    float* lp  = (float*)(ws + LP_OFF);
    bf16*  wb  = (bf16*)(ws + WB_OFF);
    bf16*  wob = (bf16*)(ws + WOB_OFF);

    prep_kernel<<<dim3(64, 5, 2), 256, 0, stream>>>(x, wqkv, wout, xt, wb, wob);
    qkv_kernel<<<dim3(64, 6, 2), 256, 0, stream>>>(xt, wb, qb, kb, vtb);
    fattn_kernel<<<dim3(1024), 256, 0, stream>>>(qb, kb, vtb, aop, lp);
    proj_kernel<<<dim3(64, 4, 2), 256, 0, stream>>>(aop, lp, wob, bout, y);
}